// Round 5
// baseline (480.394 us; speedup 1.0000x reference)
//
#include <hip/hip_runtime.h>

// SparseInputLayer: inputs [B, ND*(1+NS)] fp32.
//  - cols [0,64): channel indices (float-encoded ints in [0,384))
//  - cols [64, ...): data rows x[b][j][s]
// out[b][c][s] = sum_{j: idx[b][j]==c} x[b][j][s], shape [2048,384,121,1] fp32.
//
// One block per batch, ONE pass, NO LDS/atomics/barriers:
//  - lane j of every wave holds idx[b][j] (one coalesced 256 B load)
//  - channel c's membership mask = __ballot(myidx == c): a single v_cmp
//    into an SGPR pair — wave-uniform, no LDS latency in the loop
//  - wave w handles channels c = 4i + w; per channel: 2 coalesced dword
//    stores (s = lane and s = 64+lane). Empty channels (~85%) cost one
//    scalar branch + the stores — same inner-loop shape as
//    fillBufferAligned, which sustains 6.2 TB/s with scalar dword stores.
//  - output written exactly once: total traffic = 381 MB W + 66 MB R (min).

#define BATCH 2048
#define N_DENSE 64
#define N_SAMPLES 121
#define N_CHANNELS 384
#define ROW_IN (N_DENSE * (1 + N_SAMPLES)) // 7808 floats per input row
#define ROW_OUT (N_CHANNELS * N_SAMPLES)   // 46464 floats per output row
#define BLOCK 256

__global__ __launch_bounds__(BLOCK) void sparse_scatter_kernel(
    const float* __restrict__ in, float* __restrict__ out) {
  const int b = blockIdx.x;
  const int wave = threadIdx.x >> 6;
  const int lane = threadIdx.x & 63;

  const float* __restrict__ row = in + (size_t)b * ROW_IN;
  const int myidx = (int)row[lane];              // lane j owns dense slot j
  const float* __restrict__ x = row + N_DENSE;   // [64][121]
  float* __restrict__ o = out + (size_t)b * ROW_OUT;

  const bool has1 = (lane < N_SAMPLES - 64);     // lanes 0..56 do 2nd sample
  const int s1 = has1 ? 64 + lane : 64;          // clamped (load stays inbounds)

  for (int i = 0; i < N_CHANNELS / 4; ++i) {
    const int c = i * 4 + wave;                  // block covers 4 channels/iter
    unsigned long long m = __ballot(myidx == c); // v_cmp -> SGPR pair, uniform
    float a0 = 0.f, a1 = 0.f;
    while (m) {                                  // scalar-driven, no divergence
      const int j = __builtin_ctzll(m);
      m &= m - 1;
      a0 += x[j * N_SAMPLES + lane];             // coalesced 256 B row read
      a1 += x[j * N_SAMPLES + s1];               // coalesced 228 B row read
    }
    float* __restrict__ oc = o + c * N_SAMPLES;
    oc[lane] = a0;                               // coalesced dword store
    if (has1) oc[64 + lane] = a1;                // coalesced dword store
  }
}

extern "C" void kernel_launch(void* const* d_in, const int* in_sizes, int n_in,
                              void* d_out, int out_size, void* d_ws, size_t ws_size,
                              hipStream_t stream) {
  const float* in = (const float*)d_in[0];
  float* out = (float*)d_out;
  sparse_scatter_kernel<<<BATCH, BLOCK, 0, stream>>>(in, out);
}

// Round 6
// 439.545 us; speedup vs baseline: 1.0929x; 1.0929x over previous
//
#include <hip/hip_runtime.h>

// SparseInputLayer: inputs [B, ND*(1+NS)] fp32.
//  - cols [0,64): channel indices (float-encoded ints in [0,384))
//  - cols [64, ...): data rows x[b][j][s]
// out[b][c][s] = sum_{j: idx[b][j]==c} x[b][j][s], shape [2048,384,121,1] fp32.
//
// R1 structure (best measured: exactly-once coalesced scalar store stream,
// per-channel 64-bit membership masks in LDS) + one change: the LDS mask
// read is SOFTWARE-PIPELINED one iteration ahead, so the ~120-cycle LDS
// latency + lgkmcnt wait is overlapped by a full iteration of independent
// work instead of sitting in front of every store.

#define BATCH 2048
#define N_DENSE 64
#define N_SAMPLES 121
#define N_CHANNELS 384
#define ROW_IN (N_DENSE * (1 + N_SAMPLES)) // 7808 floats per input row
#define ROW_OUT (N_CHANNELS * N_SAMPLES)   // 46464 floats per output row
#define BLOCK 256

__global__ __launch_bounds__(BLOCK) void sparse_scatter_kernel(
    const float* __restrict__ in, float* __restrict__ out) {
  // +8 pad: the one-ahead prefetch can index up to c = 386; pad reads 0.
  __shared__ unsigned long long mask[N_CHANNELS + 8];

  const int b = blockIdx.x;
  const int tid = threadIdx.x;

  for (int c = tid; c < N_CHANNELS + 8; c += BLOCK) mask[c] = 0ull;
  __syncthreads();

  // threads 0..63 each own dense slot j; set bit j in its channel's mask
  if (tid < N_DENSE) {
    const int c = (int)in[(size_t)b * ROW_IN + tid];
    atomicOr(&mask[c], 1ull << tid);
  }
  __syncthreads();

  const float* __restrict__ x = in + (size_t)b * ROW_IN + N_DENSE; // [64][121]
  float* __restrict__ o = out + (size_t)b * ROW_OUT;               // [384][121]

  // prologue: mask for iteration 0
  int e = tid;
  int c = e / N_SAMPLES;
  int s = e - c * N_SAMPLES;
  unsigned long long m = mask[c];

  while (e < ROW_OUT) {
    // ---- prefetch iteration k+1's mask (independent of this iteration) ----
    const int e_n = e + BLOCK;
    const int c_n = e_n / N_SAMPLES;           // magic-mul div
    const int s_n = e_n - c_n * N_SAMPLES;
    const unsigned long long m_n = mask[c_n];  // LDS issue now, consumed next iter

    // ---- iteration k: bit-walk (rare; ~15% of lanes nonempty) + store ----
    float sum = 0.0f;
    unsigned long long mm = m;
    while (mm) {
      const int j = __builtin_ctzll(mm);
      mm &= mm - 1;
      sum += x[j * N_SAMPLES + s];             // L1-resident 31 KB slab
    }
    o[e] = sum;                                // coalesced dword store

    e = e_n; s = s_n; m = m_n;
  }
}

extern "C" void kernel_launch(void* const* d_in, const int* in_sizes, int n_in,
                              void* d_out, int out_size, void* d_ws, size_t ws_size,
                              hipStream_t stream) {
  const float* in = (const float*)d_in[0];
  float* out = (float*)d_out;
  sparse_scatter_kernel<<<BATCH, BLOCK, 0, stream>>>(in, out);
}